// Round 2
// baseline (7447.150 us; speedup 1.0000x reference)
//
#include <hip/hip_runtime.h>
#include <hip/hip_bf16.h>
#include <math.h>

// ---------------------------------------------------------------------------
// GPoolBlock (KataGo-style): bn+mish -> {conv3x3 reg, conv3x3 gpool} ->
// gpool(mean,scaled-mean,max) -> linear -> add -> bn+mish -> conv3x3 -> +x
// I/O tensors fp32 (per reference dtype). Internal activations bf16,
// accumulation fp32.
// ---------------------------------------------------------------------------

#define BATCH   256
#define TRUNK_C 256
#define REG_C   192
#define GPOOL_C 64
#define HH      19
#define WW      19
#define HW      361          // 19*19
#define EPS     1e-5f

typedef __hip_bfloat16 bf16;

__device__ __forceinline__ float b2f(bf16 v) { return __bfloat162float(v); }
__device__ __forceinline__ bf16  f2b(float v) { return __float2bfloat16(v); }

__device__ __forceinline__ float mish_f(float v) {
    float sp = (v > 20.0f) ? v : log1pf(expf(v));
    return v * tanhf(sp);
}

__device__ __forceinline__ void conv_store(bf16* out, size_t i, float v)  { out[i] = f2b(v); }
__device__ __forceinline__ void conv_store(float* out, size_t i, float v) { out[i] = v; }

// --------------------------- prep: fold BN params ---------------------------
// bnbuf layout (floats): [0:256] bn1_s [256:512] bn1_b
//                        [512:576] bn1b_s [576:640] bn1b_b
//                        [640:832] bn2_s  [832:1024] bn2_b
__global__ void prep_bn_kernel(const float* g1, const float* b1, const float* m1, const float* v1,
                               const float* g1b, const float* b1b, const float* m1b, const float* v1b,
                               const float* g2, const float* b2, const float* m2, const float* v2,
                               float* bnbuf) {
    int t = threadIdx.x;
    if (t < 256) {
        float s = g1[t] / sqrtf(v1[t] + EPS);
        bnbuf[t] = s;
        bnbuf[256 + t] = b1[t] - m1[t] * s;
    } else if (t < 320) {
        int c = t - 256;
        float s = g1b[c] / sqrtf(v1b[c] + EPS);
        bnbuf[512 + c] = s;
        bnbuf[576 + c] = b1b[c] - m1b[c] * s;
    } else if (t < 512) {
        int c = t - 320;
        float s = g2[c] / sqrtf(v2[c] + EPS);
        bnbuf[640 + c] = s;
        bnbuf[832 + c] = b2[c] - m2[c] * s;
    }
}

// --------------------------- elementwise bn1+mish ---------------------------
__global__ void bn1_mish_kernel(const float* __restrict__ x, const float* __restrict__ bnbuf,
                                bf16* __restrict__ act) {
    const int n = BATCH * TRUNK_C * HW;
    int i = blockIdx.x * blockDim.x + threadIdx.x;
    if (i >= n) return;
    int c = (i / HW) % TRUNK_C;
    float v = x[i];
    v = v * bnbuf[c] + bnbuf[256 + c];
    act[i] = f2b(mish_f(v));
}

// ------------------------------- direct conv --------------------------------
// One block: (batch b, 8 consecutive output channels). 384 threads cover the
// 361 output pixels. 4 input channels staged per LDS round (padded 21x21
// tiles). Weights fp32, indexed wave-uniformly -> scalar loads.
template<int CIN, bool MISH, bool RES, typename OutT>
__global__ __launch_bounds__(384)
void conv3x3_kernel(const bf16* __restrict__ in, const float* __restrict__ wf,
                    OutT* __restrict__ out,
                    const float* __restrict__ ep_scale, const float* __restrict__ ep_bias,
                    const float* __restrict__ residual, int Cout) {
    __shared__ float tile[4 * 441];          // 4 channels of 21x21 padded tile
    const int b = blockIdx.y;
    const int co_base = blockIdx.x * 8;
    const int t = threadIdx.x;

    float acc[8];
#pragma unroll
    for (int j = 0; j < 8; ++j) acc[j] = 0.0f;

    const int h = t / WW;
    const int w = t - h * WW;

    for (int ci0 = 0; ci0 < CIN; ci0 += 4) {
        __syncthreads();   // protect previous round's reads
        for (int idx = t; idx < 4 * 441; idx += 384) {
            int cc = idx / 441;
            int rem = idx - cc * 441;
            int r = rem / 21;
            int col = rem - r * 21;
            int ih = r - 1, iw = col - 1;
            float v = 0.0f;
            if ((unsigned)ih < (unsigned)HH && (unsigned)iw < (unsigned)WW)
                v = b2f(in[((b * CIN + ci0 + cc) * HH + ih) * WW + iw]);
            tile[idx] = v;
        }
        __syncthreads();
        if (t < HW) {
#pragma unroll
            for (int cc = 0; cc < 4; ++cc) {
                const float* tp = &tile[cc * 441 + h * 21 + w];
                float tv[9];
#pragma unroll
                for (int kh = 0; kh < 3; ++kh) {
#pragma unroll
                    for (int kw = 0; kw < 3; ++kw)
                        tv[kh * 3 + kw] = tp[kh * 21 + kw];
                }
                const int ci = ci0 + cc;
#pragma unroll
                for (int j = 0; j < 8; ++j) {
                    const float* wp = wf + (size_t)((co_base + j) * CIN + ci) * 9;
#pragma unroll
                    for (int k = 0; k < 9; ++k)
                        acc[j] = fmaf(tv[k], wp[k], acc[j]);
                }
            }
        }
    }

    if (t < HW) {
#pragma unroll
        for (int j = 0; j < 8; ++j) {
            int co = co_base + j;
            float v = acc[j];
            if (MISH) {
                v = v * ep_scale[co] + ep_bias[co];
                v = mish_f(v);
            }
            size_t oidx = (size_t)(b * Cout + co) * HW + t;
            if (RES) v += residual[oidx];
            conv_store(out, oidx, v);
        }
    }
}

// ------------------------------ kata gpool ----------------------------------
// pooled[b, 0:64]=mean, [64:128]=mean*0.5 ((19-14)/10), [128:192]=max
__global__ void gpool_kernel(const bf16* __restrict__ gp, float* __restrict__ pooled) {
    int b = blockIdx.x;
    int tid = threadIdx.x;          // 256
    int c = tid >> 2;
    int sub = tid & 3;
    const bf16* p = gp + (size_t)(b * GPOOL_C + c) * HW;
    float s = 0.0f, mx = -1e30f;
    for (int i = sub; i < HW; i += 4) {
        float v = b2f(p[i]);
        s += v;
        mx = fmaxf(mx, v);
    }
    s += __shfl_xor(s, 1);
    s += __shfl_xor(s, 2);
    mx = fmaxf(mx, __shfl_xor(mx, 1));
    mx = fmaxf(mx, __shfl_xor(mx, 2));
    if (sub == 0) {
        float mean = s * (1.0f / 361.0f);
        pooled[b * 192 + c] = mean;
        pooled[b * 192 + 64 + c] = mean * 0.5f;
        pooled[b * 192 + 128 + c] = mx;
    }
}

// -------------------------- tiny linear (192x192) ---------------------------
__global__ void lin_kernel(const float* __restrict__ pooled, const float* __restrict__ w_lin,
                           float* __restrict__ gpout) {
    int i = blockIdx.x * blockDim.x + threadIdx.x;     // [0, 256*192)
    if (i >= BATCH * REG_C) return;
    int b = i / REG_C;
    int oc = i - b * REG_C;
    const float* pr = pooled + b * 192;
    const float* wr = w_lin + oc * 192;
    float s = 0.0f;
    for (int j = 0; j < 192; ++j) s = fmaf(pr[j], wr[j], s);
    gpout[i] = s;
}

// ----------------------- add gpool bias + bn2 + mish ------------------------
__global__ void add_bn2_mish_kernel(const bf16* __restrict__ reg, const float* __restrict__ gpout,
                                    const float* __restrict__ bnbuf, bf16* __restrict__ out) {
    const int n = BATCH * REG_C * HW;
    int i = blockIdx.x * blockDim.x + threadIdx.x;
    if (i >= n) return;
    int bc = i / HW;                 // b*192 + c
    int c = bc % REG_C;
    float v = b2f(reg[i]) + gpout[bc];
    v = v * bnbuf[640 + c] + bnbuf[832 + c];
    out[i] = f2b(mish_f(v));
}

// ---------------------------------------------------------------------------
extern "C" void kernel_launch(void* const* d_in, const int* in_sizes, int n_in,
                              void* d_out, int out_size, void* d_ws, size_t ws_size,
                              hipStream_t stream) {
    const float* x     = (const float*)d_in[0];
    const float* bn1_g = (const float*)d_in[1];
    const float* bn1_b = (const float*)d_in[2];
    const float* bn1_m = (const float*)d_in[3];
    const float* bn1_v = (const float*)d_in[4];
    const float* w1a   = (const float*)d_in[5];
    const float* w1b   = (const float*)d_in[6];
    const float* bn1b_g = (const float*)d_in[7];
    const float* bn1b_b = (const float*)d_in[8];
    const float* bn1b_m = (const float*)d_in[9];
    const float* bn1b_v = (const float*)d_in[10];
    const float* w_lin  = (const float*)d_in[11];
    const float* bn2_g  = (const float*)d_in[12];
    const float* bn2_b  = (const float*)d_in[13];
    const float* bn2_m  = (const float*)d_in[14];
    const float* bn2_v  = (const float*)d_in[15];
    const float* w2     = (const float*)d_in[16];
    float* out = (float*)d_out;

    const size_t N_ACT1 = (size_t)BATCH * TRUNK_C * HW;   // 23,658,496
    const size_t N_REG  = (size_t)BATCH * REG_C * HW;     // 17,743,872
    const size_t N_GP   = (size_t)BATCH * GPOOL_C * HW;   //  5,914,624

    char* ws = (char*)d_ws;
    size_t off = 0;
    auto alloc = [&](size_t bytes) {
        void* p = ws + off;
        off += (bytes + 255) & ~(size_t)255;
        return p;
    };
    bf16*  act1   = (bf16*)alloc(N_ACT1 * sizeof(bf16));   // later reused by reg2
    bf16*  reg    = (bf16*)alloc(N_REG * sizeof(bf16));
    bf16*  gp     = (bf16*)alloc(N_GP * sizeof(bf16));
    float* pooled = (float*)alloc((size_t)BATCH * 192 * sizeof(float));
    float* gpout  = (float*)alloc((size_t)BATCH * 192 * sizeof(float));
    float* bnbuf  = (float*)alloc(1024 * sizeof(float));
    bf16*  reg2   = act1;   // act1 dead after conv1a/conv1b; alias to save ws
    (void)ws_size;

    // 1. fold BN params
    hipLaunchKernelGGL(prep_bn_kernel, dim3(1), dim3(512), 0, stream,
                       bn1_g, bn1_b, bn1_m, bn1_v,
                       bn1b_g, bn1b_b, bn1b_m, bn1b_v,
                       bn2_g, bn2_b, bn2_m, bn2_v, bnbuf);

    // 2. act1 = mish(bn1(x))
    {
        int n = (int)N_ACT1;
        hipLaunchKernelGGL(bn1_mish_kernel, dim3((n + 255) / 256), dim3(256), 0, stream,
                           x, bnbuf, act1);
    }

    // 3. reg = conv(act1, w1a)  [256 -> 192]
    hipLaunchKernelGGL((conv3x3_kernel<TRUNK_C, false, false, bf16>), dim3(REG_C / 8, BATCH),
                       dim3(384), 0, stream,
                       act1, w1a, reg, (const float*)nullptr, (const float*)nullptr,
                       (const float*)nullptr, REG_C);

    // 4. gp = mish(bn1b(conv(act1, w1b)))  [256 -> 64], BN+mish fused in epilogue
    hipLaunchKernelGGL((conv3x3_kernel<TRUNK_C, true, false, bf16>), dim3(GPOOL_C / 8, BATCH),
                       dim3(384), 0, stream,
                       act1, w1b, gp, bnbuf + 512, bnbuf + 576,
                       (const float*)nullptr, GPOOL_C);

    // 5. pooled = kata_gpool(gp)
    hipLaunchKernelGGL(gpool_kernel, dim3(BATCH), dim3(256), 0, stream, gp, pooled);

    // 6. gpout = pooled @ w_lin^T
    hipLaunchKernelGGL(lin_kernel, dim3((BATCH * REG_C + 255) / 256), dim3(256), 0, stream,
                       pooled, w_lin, gpout);

    // 7. reg2 = mish(bn2(reg + gpout))   (reg2 aliases act1's storage)
    {
        int n = (int)N_REG;
        hipLaunchKernelGGL(add_bn2_mish_kernel, dim3((n + 255) / 256), dim3(256), 0, stream,
                           reg, gpout, bnbuf, reg2);
    }

    // 8. out = conv(reg2, w2) + x  [192 -> 256], residual fused, fp32 out
    hipLaunchKernelGGL((conv3x3_kernel<REG_C, false, true, float>), dim3(TRUNK_C / 8, BATCH),
                       dim3(384), 0, stream,
                       reg2, w2, out, (const float*)nullptr, (const float*)nullptr,
                       x, TRUNK_C);
}

// Round 3
// 1217.034 us; speedup vs baseline: 6.1191x; 6.1191x over previous
//
#include <hip/hip_runtime.h>
#include <hip/hip_bf16.h>
#include <math.h>

// ---------------------------------------------------------------------------
// GPoolBlock via implicit-GEMM MFMA (bf16 in, fp32 acc).
// Activations kept channel-last, zero-padded [b][21*21][C] so MFMA A-frags
// are contiguous 16B loads. Weights permuted to [co][(kh*3+kw)*CIN+ci] bf16.
// conv1a/1b: A=act (D rows=pixels) -> channel-last store.
// conv2:     A=weights (D rows=co) -> channel-first fp32 store + residual.
// ---------------------------------------------------------------------------

#define BATCH   256
#define TRUNK_C 256
#define REG_C   192
#define GPOOL_C 64
#define HH      19
#define WW      19
#define HW      361
#define PP      441          // 21*21 padded pixels
#define EPS     1e-5f

typedef __hip_bfloat16 bf16;
typedef __attribute__((ext_vector_type(8))) short short8;
typedef __attribute__((ext_vector_type(4))) float floatx4;

__device__ __forceinline__ float b2f(bf16 v) { return __bfloat162float(v); }
__device__ __forceinline__ bf16  f2b(float v) { return __float2bfloat16(v); }

__device__ __forceinline__ float mish_f(float v) {
    float sp = (v > 20.0f) ? v : log1pf(expf(v));
    return v * tanhf(sp);
}

// --------------------------- prep: fold BN params ---------------------------
// bnbuf: [0:256] bn1_s [256:512] bn1_b [512:576] bn1b_s [576:640] bn1b_b
//        [640:832] bn2_s [832:1024] bn2_b
__global__ void prep_bn_kernel(const float* g1, const float* b1, const float* m1, const float* v1,
                               const float* g1b, const float* b1b, const float* m1b, const float* v1b,
                               const float* g2, const float* b2, const float* m2, const float* v2,
                               float* bnbuf) {
    int t = threadIdx.x;
    if (t < 256) {
        float s = g1[t] / sqrtf(v1[t] + EPS);
        bnbuf[t] = s;
        bnbuf[256 + t] = b1[t] - m1[t] * s;
    } else if (t < 320) {
        int c = t - 256;
        float s = g1b[c] / sqrtf(v1b[c] + EPS);
        bnbuf[512 + c] = s;
        bnbuf[576 + c] = b1b[c] - m1b[c] * s;
    } else if (t < 512) {
        int c = t - 320;
        float s = g2[c] / sqrtf(v2[c] + EPS);
        bnbuf[640 + c] = s;
        bnbuf[832 + c] = b2[c] - m2[c] * s;
    }
}

// ---------------- prep: weights fp32 [co][ci][3][3] -> bf16 [co][r*CIN+ci] --
__global__ void prep_w_kernel(const float* __restrict__ w1a, const float* __restrict__ w1b,
                              const float* __restrict__ w2,
                              bf16* __restrict__ w1a_p, bf16* __restrict__ w1b_p,
                              bf16* __restrict__ w2_p) {
    const int N1 = REG_C * TRUNK_C * 9;     // 442368
    const int N2 = GPOOL_C * TRUNK_C * 9;   // 147456
    const int N3 = TRUNK_C * REG_C * 9;     // 442368
    int total = N1 + N2 + N3;
    for (int i = blockIdx.x * blockDim.x + threadIdx.x; i < total;
         i += gridDim.x * blockDim.x) {
        if (i < N1) {
            int co = i / 2304, k = i % 2304, r = k / 256, ci = k % 256;
            w1a_p[i] = f2b(w1a[co * 2304 + ci * 9 + r]);
        } else if (i < N1 + N2) {
            int j = i - N1;
            int co = j / 2304, k = j % 2304, r = k / 256, ci = k % 256;
            w1b_p[j] = f2b(w1b[co * 2304 + ci * 9 + r]);
        } else {
            int j = i - N1 - N2;
            int co = j / 1728, k = j % 1728, r = k / 192, ci = k % 192;
            w2_p[j] = f2b(w2[co * 1728 + ci * 9 + r]);
        }
    }
}

// ---------------- zero the padded borders of act_pad and reg_pad ------------
__global__ void zero_border_kernel(bf16* __restrict__ act_pad, bf16* __restrict__ reg_pad) {
    int b = blockIdx.x;
    int t = threadIdx.x;     // 256
    for (int pp = 0; pp < PP; ++pp) {
        int r = pp / 21, c = pp % 21;
        bool border = (r == 0) | (r == 20) | (c == 0) | (c == 20);
        if (!border) continue;
        act_pad[((size_t)b * PP + pp) * TRUNK_C + t] = f2b(0.0f);
        if (t < REG_C) reg_pad[((size_t)b * PP + pp) * REG_C + t] = f2b(0.0f);
    }
}

// ------- bn1+mish + transpose: x [b][256][361] fp32 -> act_pad CL bf16 ------
__global__ void bn1_mish_t_kernel(const float* __restrict__ x, const float* __restrict__ bnbuf,
                                  bf16* __restrict__ act_pad) {
    int p = blockIdx.x;           // 0..360
    int b = blockIdx.y;
    int ci = threadIdx.x;         // 256
    float v = x[((size_t)b * TRUNK_C + ci) * HW + p];
    v = v * bnbuf[ci] + bnbuf[256 + ci];
    v = mish_f(v);
    int pp = (p / WW + 1) * 21 + (p % WW + 1);
    act_pad[((size_t)b * PP + pp) * TRUNK_C + ci] = f2b(v);
}

// --------------------- MFMA conv, channel-last output -----------------------
// A = activations (D rows = pixels), B = weights (D cols = co).
// Block = 1 wave. Tile: 64 pixels x 64 co. out layout: PADOUT? [b][441][COUT]
// (interior) : [b][361][COUT]. Optional BN+mish epilogue (per-co).
template<int CIN, int COUT, bool MISH, bool PADOUT>
__global__ __launch_bounds__(64)
void conv_cl_kernel(const bf16* __restrict__ act, const bf16* __restrict__ wp,
                    bf16* __restrict__ out,
                    const float* __restrict__ ep_scale, const float* __restrict__ ep_bias) {
    const int b    = blockIdx.x;
    const int mg   = blockIdx.y;          // pixel group (64)
    const int ng   = blockIdx.z;          // co group (64)
    const int lane = threadIdx.x;
    const int l15  = lane & 15;
    const int quad = lane >> 4;
    const int K    = 9 * CIN;
    const int NCI  = CIN / 32;

    // A rows: pixel per msub
    int hA[4], wA[4];
#pragma unroll
    for (int ms = 0; ms < 4; ++ms) {
        int p = mg * 64 + ms * 16 + l15;
        if (p > 360) p = 360;
        hA[ms] = p / WW; wA[ms] = p % WW;
    }
    // B rows: weights
    const bf16* wbase[4];
#pragma unroll
    for (int ns = 0; ns < 4; ++ns)
        wbase[ns] = wp + (size_t)(ng * 64 + ns * 16 + l15) * K + quad * 8;

    floatx4 acc[4][4];
#pragma unroll
    for (int i = 0; i < 4; ++i)
#pragma unroll
        for (int j = 0; j < 4; ++j) acc[i][j] = (floatx4){0.f, 0.f, 0.f, 0.f};

    for (int r = 0; r < 9; ++r) {
        const int kh = r / 3, kw = r % 3;
        const bf16* abase[4];
#pragma unroll
        for (int ms = 0; ms < 4; ++ms)
            abase[ms] = act + ((size_t)b * PP + (hA[ms] + kh) * 21 + (wA[ms] + kw)) * CIN + quad * 8;
        const int kroff = r * CIN;
#pragma unroll 2
        for (int c = 0; c < NCI; ++c) {
            short8 af[4], bf[4];
#pragma unroll
            for (int ms = 0; ms < 4; ++ms)
                af[ms] = *(const short8*)(abase[ms] + c * 32);
#pragma unroll
            for (int ns = 0; ns < 4; ++ns)
                bf[ns] = *(const short8*)(wbase[ns] + kroff + c * 32);
#pragma unroll
            for (int ms = 0; ms < 4; ++ms)
#pragma unroll
                for (int ns = 0; ns < 4; ++ns)
                    acc[ms][ns] = __builtin_amdgcn_mfma_f32_16x16x32_bf16(
                        af[ms], bf[ns], acc[ms][ns], 0, 0, 0);
        }
    }

    // epilogue: rows = pixels (quad*4+reg), cols = co (l15)
    float scl[4], bia[4];
    if (MISH) {
#pragma unroll
        for (int ns = 0; ns < 4; ++ns) {
            int co = ng * 64 + ns * 16 + l15;
            scl[ns] = ep_scale[co]; bia[ns] = ep_bias[co];
        }
    }
#pragma unroll
    for (int ms = 0; ms < 4; ++ms) {
#pragma unroll
        for (int rg = 0; rg < 4; ++rg) {
            int p = mg * 64 + ms * 16 + quad * 4 + rg;
            if (p > 360) continue;
            size_t pixidx;
            if (PADOUT) {
                int pp = (p / WW + 1) * 21 + (p % WW + 1);
                pixidx = (size_t)b * PP + pp;
            } else {
                pixidx = (size_t)b * HW + p;
            }
#pragma unroll
            for (int ns = 0; ns < 4; ++ns) {
                float v = acc[ms][ns][rg];
                if (MISH) v = mish_f(v * scl[ns] + bia[ns]);
                out[pixidx * COUT + ng * 64 + ns * 16 + l15] = f2b(v);
            }
        }
    }
}

// --------------------- MFMA conv2, channel-first fp32 out -------------------
// A = weights (D rows = co), B = activations (D cols = pixels). +x residual.
__global__ __launch_bounds__(64)
void conv_cf_kernel(const bf16* __restrict__ act,   // reg_pad [b][441][192]
                    const bf16* __restrict__ wp,    // [256][1728]
                    const float* __restrict__ resid,
                    float* __restrict__ out) {
    const int CIN = REG_C, COUT = TRUNK_C, K = 9 * CIN, NCI = CIN / 32;
    const int b    = blockIdx.x;
    const int cg   = blockIdx.y;          // co group (4)
    const int pg   = blockIdx.z;          // pixel group (6)
    const int lane = threadIdx.x;
    const int l15  = lane & 15;
    const int quad = lane >> 4;

    const bf16* wbase[4];
#pragma unroll
    for (int ms = 0; ms < 4; ++ms)
        wbase[ms] = wp + (size_t)(cg * 64 + ms * 16 + l15) * K + quad * 8;

    int hB[4], wB[4];
#pragma unroll
    for (int ns = 0; ns < 4; ++ns) {
        int p = pg * 64 + ns * 16 + l15;
        if (p > 360) p = 360;
        hB[ns] = p / WW; wB[ns] = p % WW;
    }

    floatx4 acc[4][4];
#pragma unroll
    for (int i = 0; i < 4; ++i)
#pragma unroll
        for (int j = 0; j < 4; ++j) acc[i][j] = (floatx4){0.f, 0.f, 0.f, 0.f};

    for (int r = 0; r < 9; ++r) {
        const int kh = r / 3, kw = r % 3;
        const bf16* bbase[4];
#pragma unroll
        for (int ns = 0; ns < 4; ++ns)
            bbase[ns] = act + ((size_t)b * PP + (hB[ns] + kh) * 21 + (wB[ns] + kw)) * CIN + quad * 8;
        const int kroff = r * CIN;
#pragma unroll 2
        for (int c = 0; c < NCI; ++c) {
            short8 af[4], bf[4];
#pragma unroll
            for (int ms = 0; ms < 4; ++ms)
                af[ms] = *(const short8*)(wbase[ms] + kroff + c * 32);
#pragma unroll
            for (int ns = 0; ns < 4; ++ns)
                bf[ns] = *(const short8*)(bbase[ns] + c * 32);
#pragma unroll
            for (int ms = 0; ms < 4; ++ms)
#pragma unroll
                for (int ns = 0; ns < 4; ++ns)
                    acc[ms][ns] = __builtin_amdgcn_mfma_f32_16x16x32_bf16(
                        af[ms], bf[ns], acc[ms][ns], 0, 0, 0);
        }
    }

    // rows = co (quad*4+reg), cols = pixel (l15)
#pragma unroll
    for (int ns = 0; ns < 4; ++ns) {
        int p = pg * 64 + ns * 16 + l15;
        if (p > 360) continue;
#pragma unroll
        for (int ms = 0; ms < 4; ++ms) {
#pragma unroll
            for (int rg = 0; rg < 4; ++rg) {
                int co = cg * 64 + ms * 16 + quad * 4 + rg;
                size_t idx = ((size_t)b * COUT + co) * HW + p;
                out[idx] = acc[ms][ns][rg] + resid[idx];
            }
        }
    }
}

// ------------------------------ kata gpool ----------------------------------
// gp channel-last [b][361][64] -> pooled[b][192]
__global__ void gpool_kernel(const bf16* __restrict__ gp, float* __restrict__ pooled) {
    __shared__ float ls[4][64], lm[4][64];
    int b = blockIdx.x;
    int t = threadIdx.x;          // 256
    int c = t & 63, sub = t >> 6;
    float s = 0.0f, mx = -1e30f;
    for (int p = sub; p < HW; p += 4) {
        float v = b2f(gp[((size_t)b * HW + p) * GPOOL_C + c]);
        s += v;
        mx = fmaxf(mx, v);
    }
    ls[sub][c] = s; lm[sub][c] = mx;
    __syncthreads();
    if (t < 64) {
        float ss = ls[0][t] + ls[1][t] + ls[2][t] + ls[3][t];
        float mm = fmaxf(fmaxf(lm[0][t], lm[1][t]), fmaxf(lm[2][t], lm[3][t]));
        float mean = ss * (1.0f / 361.0f);
        pooled[b * 192 + t] = mean;
        pooled[b * 192 + 64 + t] = mean * 0.5f;
        pooled[b * 192 + 128 + t] = mm;
    }
}

// -------------------------- tiny linear (192x192) ---------------------------
__global__ void lin_kernel(const float* __restrict__ pooled, const float* __restrict__ w_lin,
                           float* __restrict__ gpout) {
    int i = blockIdx.x * blockDim.x + threadIdx.x;
    if (i >= BATCH * REG_C) return;
    int b = i / REG_C;
    int oc = i - b * REG_C;
    const float* pr = pooled + b * 192;
    const float* wr = w_lin + oc * 192;
    float s = 0.0f;
    for (int j = 0; j < 192; ++j) s = fmaf(pr[j], wr[j], s);
    gpout[i] = s;
}

// ------------- add gpool bias + bn2 + mish, in-place on reg_pad -------------
__global__ void add_bn2_mish_kernel(bf16* __restrict__ reg_pad, const float* __restrict__ gpout,
                                    const float* __restrict__ bnbuf) {
    const int n = BATCH * HW * REG_C;
    int i = blockIdx.x * blockDim.x + threadIdx.x;
    if (i >= n) return;
    int c = i % REG_C;
    int bp = i / REG_C;
    int p = bp % HW;
    int b = bp / HW;
    int pp = (p / WW + 1) * 21 + (p % WW + 1);
    size_t idx = ((size_t)b * PP + pp) * REG_C + c;
    float v = b2f(reg_pad[idx]) + gpout[b * 192 + c];
    v = v * bnbuf[640 + c] + bnbuf[832 + c];
    reg_pad[idx] = f2b(mish_f(v));
}

// ---------------------------------------------------------------------------
extern "C" void kernel_launch(void* const* d_in, const int* in_sizes, int n_in,
                              void* d_out, int out_size, void* d_ws, size_t ws_size,
                              hipStream_t stream) {
    const float* x     = (const float*)d_in[0];
    const float* bn1_g = (const float*)d_in[1];
    const float* bn1_b = (const float*)d_in[2];
    const float* bn1_m = (const float*)d_in[3];
    const float* bn1_v = (const float*)d_in[4];
    const float* w1a   = (const float*)d_in[5];
    const float* w1b   = (const float*)d_in[6];
    const float* bn1b_g = (const float*)d_in[7];
    const float* bn1b_b = (const float*)d_in[8];
    const float* bn1b_m = (const float*)d_in[9];
    const float* bn1b_v = (const float*)d_in[10];
    const float* w_lin  = (const float*)d_in[11];
    const float* bn2_g  = (const float*)d_in[12];
    const float* bn2_b  = (const float*)d_in[13];
    const float* bn2_m  = (const float*)d_in[14];
    const float* bn2_v  = (const float*)d_in[15];
    const float* w2     = (const float*)d_in[16];
    float* out = (float*)d_out;

    char* ws = (char*)d_ws;
    size_t off = 0;
    auto alloc = [&](size_t bytes) {
        void* p = ws + off;
        off += (bytes + 255) & ~(size_t)255;
        return p;
    };
    bf16*  act_pad = (bf16*)alloc((size_t)BATCH * PP * TRUNK_C * sizeof(bf16));  // ~55 MB
    bf16*  reg_pad = (bf16*)alloc((size_t)BATCH * PP * REG_C * sizeof(bf16));    // ~41 MB
    bf16*  gp      = (bf16*)alloc((size_t)BATCH * HW * GPOOL_C * sizeof(bf16));  // ~11 MB
    bf16*  w1a_p   = (bf16*)alloc((size_t)REG_C * TRUNK_C * 9 * sizeof(bf16));
    bf16*  w1b_p   = (bf16*)alloc((size_t)GPOOL_C * TRUNK_C * 9 * sizeof(bf16));
    bf16*  w2_p    = (bf16*)alloc((size_t)TRUNK_C * REG_C * 9 * sizeof(bf16));
    float* pooled  = (float*)alloc((size_t)BATCH * 192 * sizeof(float));
    float* gpout   = (float*)alloc((size_t)BATCH * 192 * sizeof(float));
    float* bnbuf   = (float*)alloc(1024 * sizeof(float));
    (void)ws_size;

    // 1. fold BN params; permute+cast weights; zero pad borders
    hipLaunchKernelGGL(prep_bn_kernel, dim3(1), dim3(512), 0, stream,
                       bn1_g, bn1_b, bn1_m, bn1_v,
                       bn1b_g, bn1b_b, bn1b_m, bn1b_v,
                       bn2_g, bn2_b, bn2_m, bn2_v, bnbuf);
    hipLaunchKernelGGL(prep_w_kernel, dim3(1024), dim3(256), 0, stream,
                       w1a, w1b, w2, w1a_p, w1b_p, w2_p);
    hipLaunchKernelGGL(zero_border_kernel, dim3(BATCH), dim3(256), 0, stream,
                       act_pad, reg_pad);

    // 2. act_pad = mish(bn1(x)), transposed to channel-last padded
    hipLaunchKernelGGL(bn1_mish_t_kernel, dim3(HW, BATCH), dim3(256), 0, stream,
                       x, bnbuf, act_pad);

    // 3. reg_pad = conv(act_pad, w1a)  [256->192], channel-last padded out
    hipLaunchKernelGGL((conv_cl_kernel<TRUNK_C, REG_C, false, true>),
                       dim3(BATCH, 6, 3), dim3(64), 0, stream,
                       act_pad, w1a_p, reg_pad, (const float*)nullptr, (const float*)nullptr);

    // 4. gp = mish(bn1b(conv(act_pad, w1b)))  [256->64], channel-last out
    hipLaunchKernelGGL((conv_cl_kernel<TRUNK_C, GPOOL_C, true, false>),
                       dim3(BATCH, 6, 1), dim3(64), 0, stream,
                       act_pad, w1b_p, gp, bnbuf + 512, bnbuf + 576);

    // 5. pooled = kata_gpool(gp)
    hipLaunchKernelGGL(gpool_kernel, dim3(BATCH), dim3(256), 0, stream, gp, pooled);

    // 6. gpout = pooled @ w_lin^T
    hipLaunchKernelGGL(lin_kernel, dim3((BATCH * REG_C + 255) / 256), dim3(256), 0, stream,
                       pooled, w_lin, gpout);

    // 7. reg_pad = mish(bn2(reg_pad + gpout)) in-place (interior only)
    {
        int n = BATCH * HW * REG_C;
        hipLaunchKernelGGL(add_bn2_mish_kernel, dim3((n + 255) / 256), dim3(256), 0, stream,
                           reg_pad, gpout, bnbuf);
    }

    // 8. out = conv(reg_pad, w2) + x  [192->256], channel-first fp32
    hipLaunchKernelGGL(conv_cf_kernel, dim3(BATCH, 4, 6), dim3(64), 0, stream,
                       reg_pad, w2_p, x, out);
}

// Round 5
// 1210.008 us; speedup vs baseline: 6.1546x; 1.0058x over previous
//
#include <hip/hip_runtime.h>
#include <hip/hip_bf16.h>
#include <math.h>

// ---------------------------------------------------------------------------
// GPoolBlock via implicit-GEMM MFMA (bf16 in, fp32 acc), round 5:
//  - depth-2 software-pipelined K-loop (double-buffered frags)
//  - multi-wave blocks (occupancy + L1 address sharing)
//  - conv1b->gpool->lin first, gpout+bn2+mish fused into conv1a epilogue
//  - LDS-tiled bn1+mish transpose (FIXED: 32 channel passes, XOR-swizzled LDS)
// Layouts: act channel-last zero-padded [b][441][C]; weights [co][tap*CIN+ci].
// ---------------------------------------------------------------------------

#define BATCH   256
#define TRUNK_C 256
#define REG_C   192
#define GPOOL_C 64
#define HH      19
#define WW      19
#define HW      361
#define PP      441          // 21*21 padded pixels
#define EPS     1e-5f

typedef __hip_bfloat16 bf16;
typedef __attribute__((ext_vector_type(8))) short short8;
typedef __attribute__((ext_vector_type(4))) float floatx4;

__device__ __forceinline__ float b2f(bf16 v) { return __bfloat162float(v); }
__device__ __forceinline__ bf16  f2b(float v) { return __float2bfloat16(v); }

__device__ __forceinline__ float mish_f(float v) {
    float sp = (v > 20.0f) ? v : log1pf(expf(v));
    return v * tanhf(sp);
}

// --------------------------- prep: fold BN params ---------------------------
// bnbuf: [0:256] bn1_s [256:512] bn1_b [512:576] bn1b_s [576:640] bn1b_b
//        [640:832] bn2_s [832:1024] bn2_b
__global__ void prep_bn_kernel(const float* g1, const float* b1, const float* m1, const float* v1,
                               const float* g1b, const float* b1b, const float* m1b, const float* v1b,
                               const float* g2, const float* b2, const float* m2, const float* v2,
                               float* bnbuf) {
    int t = threadIdx.x;
    if (t < 256) {
        float s = g1[t] / sqrtf(v1[t] + EPS);
        bnbuf[t] = s;
        bnbuf[256 + t] = b1[t] - m1[t] * s;
    } else if (t < 320) {
        int c = t - 256;
        float s = g1b[c] / sqrtf(v1b[c] + EPS);
        bnbuf[512 + c] = s;
        bnbuf[576 + c] = b1b[c] - m1b[c] * s;
    } else if (t < 512) {
        int c = t - 320;
        float s = g2[c] / sqrtf(v2[c] + EPS);
        bnbuf[640 + c] = s;
        bnbuf[832 + c] = b2[c] - m2[c] * s;
    }
}

// ---------------- prep: weights fp32 [co][ci][3][3] -> bf16 [co][r*CIN+ci] --
__global__ void prep_w_kernel(const float* __restrict__ w1a, const float* __restrict__ w1b,
                              const float* __restrict__ w2,
                              bf16* __restrict__ w1a_p, bf16* __restrict__ w1b_p,
                              bf16* __restrict__ w2_p) {
    const int N1 = REG_C * TRUNK_C * 9;
    const int N2 = GPOOL_C * TRUNK_C * 9;
    const int N3 = TRUNK_C * REG_C * 9;
    int total = N1 + N2 + N3;
    for (int i = blockIdx.x * blockDim.x + threadIdx.x; i < total;
         i += gridDim.x * blockDim.x) {
        if (i < N1) {
            int co = i / 2304, k = i % 2304, r = k / 256, ci = k % 256;
            w1a_p[i] = f2b(w1a[co * 2304 + ci * 9 + r]);
        } else if (i < N1 + N2) {
            int j = i - N1;
            int co = j / 2304, k = j % 2304, r = k / 256, ci = k % 256;
            w1b_p[j] = f2b(w1b[co * 2304 + ci * 9 + r]);
        } else {
            int j = i - N1 - N2;
            int co = j / 1728, k = j % 1728, r = k / 192, ci = k % 192;
            w2_p[j] = f2b(w2[co * 1728 + ci * 9 + r]);
        }
    }
}

// ---------------- zero the padded borders of act_pad and reg_pad ------------
__global__ void zero_border_kernel(bf16* __restrict__ act_pad, bf16* __restrict__ reg_pad) {
    int b = blockIdx.x;
    int t = threadIdx.x;     // 256
    for (int pp = 0; pp < PP; ++pp) {
        int r = pp / 21, c = pp % 21;
        bool border = (r == 0) | (r == 20) | (c == 0) | (c == 20);
        if (!border) continue;
        act_pad[((size_t)b * PP + pp) * TRUNK_C + t] = f2b(0.0f);
        if (t < REG_C) reg_pad[((size_t)b * PP + pp) * REG_C + t] = f2b(0.0f);
    }
}

// ------- bn1+mish + LDS transpose: x [b][256][361] fp32 -> act_pad CL bf16 --
// LDS element (ci, px) stored at lds[ci][px ^ (ci>>3)] -> both phases
// conflict-free (2 lanes/bank across wave halves, which is free).
__global__ __launch_bounds__(256)
void bn1_mish_t_kernel(const float* __restrict__ x, const float* __restrict__ bnbuf,
                       bf16* __restrict__ act_pad) {
    __shared__ float lds[256][32];    // 32 KB, XOR-swizzled columns
    int pc = blockIdx.x;              // pixel chunk of 32 (12 chunks)
    int b  = blockIdx.y;
    int t  = threadIdx.x;
    int p0 = pc * 32;
    int px = t & 31;
#pragma unroll
    for (int it = 0; it < 32; ++it) {          // 32 passes x 8 channels = 256
        int ci = it * 8 + (t >> 5);
        int p  = p0 + px;
        float v = 0.0f;
        if (p < HW) v = x[((size_t)b * TRUNK_C + ci) * HW + p];
        v = v * bnbuf[ci] + bnbuf[256 + ci];
        lds[ci][px ^ (ci >> 3)] = mish_f(v);
    }
    __syncthreads();
#pragma unroll
    for (int it = 0; it < 4; ++it) {
        int pl = it * 8 + (t >> 5);
        int p  = p0 + pl;
        if (p >= HW) continue;
        int ch = t & 31;                       // channel block: ch*8 .. ch*8+7
        short8 vv;
#pragma unroll
        for (int j = 0; j < 8; ++j) {
            bf16 h = f2b(lds[ch * 8 + j][pl ^ ch]);
            short s;
            __builtin_memcpy(&s, &h, 2);
            vv[j] = s;
        }
        int pp = (p / WW + 1) * 21 + (p % WW + 1);
        *(short8*)(act_pad + ((size_t)b * PP + pp) * TRUNK_C + ch * 8) = vv;
    }
}

// --------------------- MFMA conv, channel-last output -----------------------
// A = activations (D rows = pixels), B = weights (D cols = co).
// WV waves/block; tile per wave: (MS*16) pixels x 64 co.
// EPI: 0 none, 1 bn+mish, 2 gpout-add + bn+mish.
template<int CIN, int COUT, int MS, int NNG, int WV, int EPI, bool PADOUT>
__global__ __launch_bounds__(WV * 64)
void conv_cl_kernel(const bf16* __restrict__ act, const bf16* __restrict__ wp,
                    bf16* __restrict__ out,
                    const float* __restrict__ ep_scale, const float* __restrict__ ep_bias,
                    const float* __restrict__ gpout) {
    const int b    = blockIdx.x;
    const int wave = threadIdx.x >> 6;
    const int lane = threadIdx.x & 63;
    const int tile = blockIdx.y * WV + wave;
    const int ng   = tile % NNG;
    const int mg   = tile / NNG;
    const int l15  = lane & 15;
    const int quad = lane >> 4;
    const int K    = 9 * CIN;
    const int NCI  = CIN / 32;
    const int NK   = 9 * NCI;

    const bf16* abase[MS];
#pragma unroll
    for (int ms = 0; ms < MS; ++ms) {
        int p = mg * (MS * 16) + ms * 16 + l15;
        if (p > 360) p = 360;
        abase[ms] = act + ((size_t)b * PP + (p / WW) * 21 + (p % WW)) * CIN + quad * 8;
    }
    const bf16* wbase[4];
#pragma unroll
    for (int ns = 0; ns < 4; ++ns)
        wbase[ns] = wp + (size_t)(ng * 64 + ns * 16 + l15) * K + quad * 8;

    floatx4 acc[MS][4];
#pragma unroll
    for (int i = 0; i < MS; ++i)
#pragma unroll
        for (int j = 0; j < 4; ++j) acc[i][j] = (floatx4){0.f, 0.f, 0.f, 0.f};

    short8 afA[MS], bfA[4], afB[MS], bfB[4];
    auto load_chunk = [&](int kk, short8* af, short8* bf) {
        int r = kk / NCI, c = kk - r * NCI;
        int rh = r / 3, rw = r - rh * 3;
        int aoff = (rh * 21 + rw) * CIN + c * 32;
#pragma unroll
        for (int ms = 0; ms < MS; ++ms) af[ms] = *(const short8*)(abase[ms] + aoff);
#pragma unroll
        for (int ns = 0; ns < 4; ++ns) bf[ns] = *(const short8*)(wbase[ns] + kk * 32);
    };
    auto do_mfma = [&](short8* af, short8* bf) {
#pragma unroll
        for (int ms = 0; ms < MS; ++ms)
#pragma unroll
            for (int ns = 0; ns < 4; ++ns)
                acc[ms][ns] = __builtin_amdgcn_mfma_f32_16x16x32_bf16(
                    af[ms], bf[ns], acc[ms][ns], 0, 0, 0);
    };

    load_chunk(0, afA, bfA);
    load_chunk(1, afB, bfB);
    for (int kk = 0; kk < NK; kk += 2) {
        do_mfma(afA, bfA);
        if (kk + 2 < NK) load_chunk(kk + 2, afA, bfA);
        do_mfma(afB, bfB);
        if (kk + 3 < NK) load_chunk(kk + 3, afB, bfB);
    }

    // epilogue: rows = pixels (quad*4+rg), cols = co (l15)
    float scl[4], bia[4], gpo[4];
#pragma unroll
    for (int ns = 0; ns < 4; ++ns) {
        int co = ng * 64 + ns * 16 + l15;
        if (EPI >= 1) { scl[ns] = ep_scale[co]; bia[ns] = ep_bias[co]; }
        if (EPI == 2) gpo[ns] = gpout[b * REG_C + co];
    }
#pragma unroll
    for (int ms = 0; ms < MS; ++ms) {
#pragma unroll
        for (int rg = 0; rg < 4; ++rg) {
            int p = mg * (MS * 16) + ms * 16 + quad * 4 + rg;
            if (p > 360) continue;
            size_t pixidx;
            if (PADOUT) {
                int pp = (p / WW + 1) * 21 + (p % WW + 1);
                pixidx = (size_t)b * PP + pp;
            } else {
                pixidx = (size_t)b * HW + p;
            }
#pragma unroll
            for (int ns = 0; ns < 4; ++ns) {
                float v = acc[ms][ns][rg];
                if (EPI == 2) v += gpo[ns];
                if (EPI >= 1) v = mish_f(v * scl[ns] + bia[ns]);
                out[pixidx * COUT + ng * 64 + ns * 16 + l15] = f2b(v);
            }
        }
    }
}

// --------------------- MFMA conv2, channel-first fp32 out -------------------
// A = weights (D rows = co), B = activations (D cols = pixels). +resid.
// Block = 6 waves = the 6 pixel groups of one (b, co-group) -> full-row writes.
__global__ __launch_bounds__(384)
void conv_cf_kernel(const bf16* __restrict__ act,   // reg_pad [b][441][192]
                    const bf16* __restrict__ wp,    // [256][1728]
                    const float* __restrict__ resid,
                    float* __restrict__ out) {
    const int CIN = REG_C, COUT = TRUNK_C, K = 9 * CIN, NCI = CIN / 32, NK = 9 * NCI;
    const int b    = blockIdx.x;
    const int cg   = blockIdx.y;          // co group (4)
    const int pg   = threadIdx.x >> 6;    // pixel group = wave (6)
    const int lane = threadIdx.x & 63;
    const int l15  = lane & 15;
    const int quad = lane >> 4;

    const bf16* wbase[4];
#pragma unroll
    for (int ms = 0; ms < 4; ++ms)
        wbase[ms] = wp + (size_t)(cg * 64 + ms * 16 + l15) * K + quad * 8;

    const bf16* bbase[4];
#pragma unroll
    for (int ns = 0; ns < 4; ++ns) {
        int p = pg * 64 + ns * 16 + l15;
        if (p > 360) p = 360;
        bbase[ns] = act + ((size_t)b * PP + (p / WW) * 21 + (p % WW)) * CIN + quad * 8;
    }

    floatx4 acc[4][4];
#pragma unroll
    for (int i = 0; i < 4; ++i)
#pragma unroll
        for (int j = 0; j < 4; ++j) acc[i][j] = (floatx4){0.f, 0.f, 0.f, 0.f};

    short8 afA[4], bfA[4], afB[4], bfB[4];
    auto load_chunk = [&](int kk, short8* af, short8* bf) {
        int r = kk / NCI, c = kk - r * NCI;
        int rh = r / 3, rw = r - rh * 3;
        int boff = (rh * 21 + rw) * CIN + c * 32;
#pragma unroll
        for (int ms = 0; ms < 4; ++ms) af[ms] = *(const short8*)(wbase[ms] + kk * 32);
#pragma unroll
        for (int ns = 0; ns < 4; ++ns) bf[ns] = *(const short8*)(bbase[ns] + boff);
    };
    auto do_mfma = [&](short8* af, short8* bf) {
#pragma unroll
        for (int ms = 0; ms < 4; ++ms)
#pragma unroll
            for (int ns = 0; ns < 4; ++ns)
                acc[ms][ns] = __builtin_amdgcn_mfma_f32_16x16x32_bf16(
                    af[ms], bf[ns], acc[ms][ns], 0, 0, 0);
    };

    load_chunk(0, afA, bfA);
    load_chunk(1, afB, bfB);
    for (int kk = 0; kk < NK; kk += 2) {
        do_mfma(afA, bfA);
        if (kk + 2 < NK) load_chunk(kk + 2, afA, bfA);
        do_mfma(afB, bfB);
        if (kk + 3 < NK) load_chunk(kk + 3, afB, bfB);
    }

    // rows = co (quad*4+rg), cols = pixel (l15)
#pragma unroll
    for (int ns = 0; ns < 4; ++ns) {
        int p = pg * 64 + ns * 16 + l15;
        if (p > 360) continue;
#pragma unroll
        for (int ms = 0; ms < 4; ++ms) {
#pragma unroll
            for (int rg = 0; rg < 4; ++rg) {
                int co = cg * 64 + ms * 16 + quad * 4 + rg;
                size_t idx = ((size_t)b * COUT + co) * HW + p;
                out[idx] = acc[ms][ns][rg] + resid[idx];
            }
        }
    }
}

// ------------------------------ kata gpool ----------------------------------
__global__ void gpool_kernel(const bf16* __restrict__ gp, float* __restrict__ pooled) {
    __shared__ float ls[4][64], lm[4][64];
    int b = blockIdx.x;
    int t = threadIdx.x;          // 256
    int c = t & 63, sub = t >> 6;
    float s = 0.0f, mx = -1e30f;
    for (int p = sub; p < HW; p += 4) {
        float v = b2f(gp[((size_t)b * HW + p) * GPOOL_C + c]);
        s += v;
        mx = fmaxf(mx, v);
    }
    ls[sub][c] = s; lm[sub][c] = mx;
    __syncthreads();
    if (t < 64) {
        float ss = ls[0][t] + ls[1][t] + ls[2][t] + ls[3][t];
        float mm = fmaxf(fmaxf(lm[0][t], lm[1][t]), fmaxf(lm[2][t], lm[3][t]));
        float mean = ss * (1.0f / 361.0f);
        pooled[b * 192 + t] = mean;
        pooled[b * 192 + 64 + t] = mean * 0.5f;
        pooled[b * 192 + 128 + t] = mm;
    }
}

// -------------------------- tiny linear (192x192) ---------------------------
__global__ void lin_kernel(const float* __restrict__ pooled, const float* __restrict__ w_lin,
                           float* __restrict__ gpout) {
    int i = blockIdx.x * blockDim.x + threadIdx.x;
    if (i >= BATCH * REG_C) return;
    int b = i / REG_C;
    int oc = i - b * REG_C;
    const float* pr = pooled + b * 192;
    const float* wr = w_lin + oc * 192;
    float s = 0.0f;
    for (int j = 0; j < 192; ++j) s = fmaf(pr[j], wr[j], s);
    gpout[i] = s;
}

// ---------------------------------------------------------------------------
extern "C" void kernel_launch(void* const* d_in, const int* in_sizes, int n_in,
                              void* d_out, int out_size, void* d_ws, size_t ws_size,
                              hipStream_t stream) {
    const float* x     = (const float*)d_in[0];
    const float* bn1_g = (const float*)d_in[1];
    const float* bn1_b = (const float*)d_in[2];
    const float* bn1_m = (const float*)d_in[3];
    const float* bn1_v = (const float*)d_in[4];
    const float* w1a   = (const float*)d_in[5];
    const float* w1b   = (const float*)d_in[6];
    const float* bn1b_g = (const float*)d_in[7];
    const float* bn1b_b = (const float*)d_in[8];
    const float* bn1b_m = (const float*)d_in[9];
    const float* bn1b_v = (const float*)d_in[10];
    const float* w_lin  = (const float*)d_in[11];
    const float* bn2_g  = (const float*)d_in[12];
    const float* bn2_b  = (const float*)d_in[13];
    const float* bn2_m  = (const float*)d_in[14];
    const float* bn2_v  = (const float*)d_in[15];
    const float* w2     = (const float*)d_in[16];
    float* out = (float*)d_out;

    char* ws = (char*)d_ws;
    size_t off = 0;
    auto alloc = [&](size_t bytes) {
        void* p = ws + off;
        off += (bytes + 255) & ~(size_t)255;
        return p;
    };
    bf16*  act_pad = (bf16*)alloc((size_t)BATCH * PP * TRUNK_C * sizeof(bf16));
    bf16*  reg_pad = (bf16*)alloc((size_t)BATCH * PP * REG_C * sizeof(bf16));
    bf16*  gp      = (bf16*)alloc((size_t)BATCH * HW * GPOOL_C * sizeof(bf16));
    bf16*  w1a_p   = (bf16*)alloc((size_t)REG_C * TRUNK_C * 9 * sizeof(bf16));
    bf16*  w1b_p   = (bf16*)alloc((size_t)GPOOL_C * TRUNK_C * 9 * sizeof(bf16));
    bf16*  w2_p    = (bf16*)alloc((size_t)TRUNK_C * REG_C * 9 * sizeof(bf16));
    float* pooled  = (float*)alloc((size_t)BATCH * 192 * sizeof(float));
    float* gpout   = (float*)alloc((size_t)BATCH * 192 * sizeof(float));
    float* bnbuf   = (float*)alloc(1024 * sizeof(float));
    (void)ws_size;

    // 1. prep
    hipLaunchKernelGGL(prep_bn_kernel, dim3(1), dim3(512), 0, stream,
                       bn1_g, bn1_b, bn1_m, bn1_v,
                       bn1b_g, bn1b_b, bn1b_m, bn1b_v,
                       bn2_g, bn2_b, bn2_m, bn2_v, bnbuf);
    hipLaunchKernelGGL(prep_w_kernel, dim3(1024), dim3(256), 0, stream,
                       w1a, w1b, w2, w1a_p, w1b_p, w2_p);
    hipLaunchKernelGGL(zero_border_kernel, dim3(BATCH), dim3(256), 0, stream,
                       act_pad, reg_pad);

    // 2. act_pad = mish(bn1(x)), LDS-tiled transpose to channel-last padded
    hipLaunchKernelGGL(bn1_mish_t_kernel, dim3(12, BATCH), dim3(256), 0, stream,
                       x, bnbuf, act_pad);

    // 3. gp = mish(bn1b(conv(act_pad, w1b)))  [256->64], 32px x 64co tiles
    hipLaunchKernelGGL((conv_cl_kernel<TRUNK_C, GPOOL_C, 2, 1, 2, 1, false>),
                       dim3(BATCH, 6), dim3(128), 0, stream,
                       act_pad, w1b_p, gp, bnbuf + 512, bnbuf + 576, (const float*)nullptr);

    // 4. pooled = kata_gpool(gp); gpout = pooled @ w_lin^T
    hipLaunchKernelGGL(gpool_kernel, dim3(BATCH), dim3(256), 0, stream, gp, pooled);
    hipLaunchKernelGGL(lin_kernel, dim3((BATCH * REG_C + 255) / 256), dim3(256), 0, stream,
                       pooled, w_lin, gpout);

    // 5. reg_pad = mish(bn2(conv(act_pad, w1a) + gpout))  [256->192], fused epi
    hipLaunchKernelGGL((conv_cl_kernel<TRUNK_C, REG_C, 4, 3, 3, 2, true>),
                       dim3(BATCH, 6), dim3(192), 0, stream,
                       act_pad, w1a_p, reg_pad, bnbuf + 640, bnbuf + 832, gpout);

    // 6. out = conv(reg_pad, w2) + x  [192->256], channel-first fp32
    hipLaunchKernelGGL(conv_cf_kernel, dim3(BATCH, 4), dim3(384), 0, stream,
                       reg_pad, w2_p, x, out);
}